// Round 1
// baseline (1814.555 us; speedup 1.0000x reference)
//
#include <hip/hip_runtime.h>
#include <hip/hip_bf16.h>
#include <stdint.h>

#define N_USER 100000
#define N_ITEM 50000
#define NTOT   150000
#define NEDGE  1200000
#define D      64
#define OUTD   256
#define NEG    0.01f
#define NBLK   586   // ceil(150000/256)

// Build E = concat(user_emb, item_emb) and write output chunk 0 (raw emb, fp32)
__global__ void k_init(const float* __restrict__ ue, const float* __restrict__ ie,
                       float* __restrict__ E, float* __restrict__ out) {
    int t = blockIdx.x * blockDim.x + threadIdx.x;
    if (t >= NTOT * 16) return;
    int r = t >> 4, q = t & 15;
    const float* src = (r < N_USER) ? (ue + (size_t)r * D)
                                    : (ie + (size_t)(r - N_USER) * D);
    float4 v = *(const float4*)(src + q * 4);
    *(float4*)(E + (size_t)r * D + q * 4) = v;
    *(float4*)(out + (size_t)r * OUTD + q * 4) = v;
}

__global__ void k_hist(const int* __restrict__ row, int* __restrict__ cnt) {
    int e = blockIdx.x * blockDim.x + threadIdx.x;
    if (e < NEDGE) atomicAdd(&cnt[row[e]], 1);
}

// Phase A: per-block (256) partial sums of counts
__global__ void k_scan_a(const int* __restrict__ cnt, int* __restrict__ part) {
    __shared__ int s[4];
    int i = blockIdx.x * 256 + threadIdx.x;
    int v = (i < NTOT) ? cnt[i] : 0;
    for (int off = 32; off; off >>= 1) v += __shfl_down(v, off, 64);
    if ((threadIdx.x & 63) == 0) s[threadIdx.x >> 6] = v;
    __syncthreads();
    if (threadIdx.x == 0) part[blockIdx.x] = s[0] + s[1] + s[2] + s[3];
}

// Phase B: single-block exclusive scan of NBLK partials
__global__ void k_scan_b(int* __restrict__ part) {
    __shared__ int s[1024];
    int t = threadIdx.x;
    int v = (t < NBLK) ? part[t] : 0;
    s[t] = v;
    __syncthreads();
    for (int off = 1; off < 1024; off <<= 1) {
        int x = (t >= off) ? s[t - off] : 0;
        __syncthreads();
        s[t] += x;
        __syncthreads();
    }
    if (t < NBLK) part[t] = s[t] - v;  // exclusive
}

// Phase C: in-block exclusive scan + block base -> offsets and cursor copy
__global__ void k_scan_c(const int* __restrict__ cnt, const int* __restrict__ part,
                         int* __restrict__ offs, int* __restrict__ cur) {
    __shared__ int ws[4];
    int i = blockIdx.x * 256 + threadIdx.x;
    int v = (i < NTOT) ? cnt[i] : 0;
    int lane = threadIdx.x & 63, w = threadIdx.x >> 6;
    int x = v;
    for (int o = 1; o < 64; o <<= 1) {
        int y = __shfl_up(x, o, 64);
        if (lane >= o) x += y;
    }
    if (lane == 63) ws[w] = x;
    __syncthreads();
    int base = part[blockIdx.x];
    for (int k = 0; k < w; k++) base += ws[k];
    int excl = base + x - v;
    if (i < NTOT) { offs[i] = excl; cur[i] = excl; }
    if (i == 0) offs[NTOT] = NEDGE;
}

__global__ void k_scatter(const int* __restrict__ row, const int* __restrict__ col,
                          const float* __restrict__ val, int* __restrict__ cur,
                          int* __restrict__ ccol, float* __restrict__ cval) {
    int e = blockIdx.x * blockDim.x + threadIdx.x;
    if (e >= NEDGE) return;
    int r = row[e];
    int p = atomicAdd(&cur[r], 1);
    ccol[p] = col[e];
    cval[p] = val[e];
}

// front = (H + I) @ E : wave per row, lane per dim
__global__ void k_spmm(const float* __restrict__ E, const int* __restrict__ offs,
                       const int* __restrict__ ccol, const float* __restrict__ cval,
                       float* __restrict__ front) {
    int r = blockIdx.x * (blockDim.x >> 6) + (threadIdx.x >> 6);
    int d = threadIdx.x & 63;
    if (r >= NTOT) return;
    int s = offs[r], e = offs[r + 1];
    float acc = E[(size_t)r * D + d];
    for (int p = s; p < e; ++p) {
        int   c = ccol[p];
        float v = cval[p];
        acc += v * E[(size_t)c * D + d];
    }
    front[(size_t)r * D + d] = acc;
}

// Per-row: fc = lrelu(front@Wf^T + bf); back = lrelu((E*front)@Wb^T + bb);
// E_new = fc + back (in place, UNNORMALIZED for next layer);
// out chunk = E_new / max(||E_new||, eps).
//
// Round-3 lesson (rocprof): the o[64] array was runtime-indexed (j loop not
// unrolled) -> scratch; VGPR_Count=72 and WRITE_SIZE 190MB (ideal 77MB)
// showed ~115MB/dispatch of spill traffic. Fix: NO o[] array. Outputs are
// produced 4-at-a-time (jj fully unrolled -> all-static indexing), stored
// straight to E; nsq accumulated on the fly; epilogue re-reads the just-
// written E row (L1/L2-hit, 256B/thread) to emit the normalized out chunk.
// f[]/g[] are all-static -> promoted (~165 VGPR under the 256 cap).
// #pragma unroll 1 on the j4 loop keeps code ~4KB (full unroll = 64KB, L1I
// is 32KB). Weight/bias addressing stays wave-uniform -> s_load streams.
__global__ __launch_bounds__(256, 2) void k_rowmv(
    const float* __restrict__ front, float* __restrict__ E,
    const float* __restrict__ Wf, const float* __restrict__ bfv,
    const float* __restrict__ Wb, const float* __restrict__ bbv,
    float* __restrict__ out, int chunk) {
    int r = blockIdx.x * blockDim.x + threadIdx.x;
    if (r >= NTOT) return;
    float f[D], g[D];
    const float* fp = front + (size_t)r * D;
    float* erow = E + (size_t)r * D;
    #pragma unroll
    for (int q = 0; q < 16; q++) {
        float4 a = *(const float4*)(fp + q * 4);
        float4 b = *(const float4*)(erow + q * 4);
        f[q*4+0] = a.x; f[q*4+1] = a.y; f[q*4+2] = a.z; f[q*4+3] = a.w;
        g[q*4+0] = a.x*b.x; g[q*4+1] = a.y*b.y; g[q*4+2] = a.z*b.z; g[q*4+3] = a.w*b.w;
    }
    float nsq = 0.f;
    #pragma unroll 1
    for (int j4 = 0; j4 < 16; j4++) {
        float en[4];
        #pragma unroll
        for (int jj = 0; jj < 4; jj++) {
            int j = j4 * 4 + jj;
            const float* wf = Wf + j * D;
            const float* wb = Wb + j * D;
            float aF0 = bfv[j], aF1 = 0.f, aB0 = bbv[j], aB1 = 0.f;
            #pragma unroll
            for (int k = 0; k < D; k += 2) {
                aF0 = fmaf(wf[k],     f[k],     aF0);
                aF1 = fmaf(wf[k + 1], f[k + 1], aF1);
                aB0 = fmaf(wb[k],     g[k],     aB0);
                aB1 = fmaf(wb[k + 1], g[k + 1], aB1);
            }
            float aF = aF0 + aF1, aB = aB0 + aB1;
            float vF = (aF > 0.f) ? aF : NEG * aF;
            float vB = (aB > 0.f) ? aB : NEG * aB;
            float e = vF + vB;
            en[jj] = e;
            nsq += e * e;
        }
        float4 u;
        u.x = en[0]; u.y = en[1]; u.z = en[2]; u.w = en[3];
        *(float4*)(erow + j4 * 4) = u;   // unnormalized E for next layer
    }
    float inv = 1.0f / fmaxf(sqrtf(nsq), 1e-12f);
    float* orow = out + (size_t)r * OUTD + (size_t)chunk * D;
    #pragma unroll
    for (int q = 0; q < 16; q++) {
        float4 u = *(const float4*)(erow + q * 4);   // L1/L2 hit (just wrote it)
        float4 w;
        w.x = u.x * inv; w.y = u.y * inv; w.z = u.z * inv; w.w = u.w * inv;
        *(float4*)(orow + q * 4) = w;
    }
}

extern "C" void kernel_launch(void* const* d_in, const int* in_sizes, int n_in,
                              void* d_out, int out_size, void* d_ws, size_t ws_size,
                              hipStream_t stream) {
    const float* ue   = (const float*)d_in[0];
    const float* ie   = (const float*)d_in[1];
    const int*   erow = (const int*)d_in[2];
    const int*   ecol = (const int*)d_in[3];
    const float* eval = (const float*)d_in[4];
    const float* Wf   = (const float*)d_in[5];
    const float* bfv  = (const float*)d_in[6];
    const float* Wb   = (const float*)d_in[7];
    const float* bbv  = (const float*)d_in[8];
    float* out = (float*)d_out;

    float* E     = (float*)d_ws;                    // NTOT*D
    float* front = E + (size_t)NTOT * D;            // NTOT*D
    float* invn  = front + (size_t)NTOT * D;        // NTOT (unused now, kept for layout)
    int*   cnt   = (int*)(invn + NTOT);             // NTOT
    int*   offs  = cnt + NTOT;                      // NTOT+1
    int*   cur   = offs + NTOT + 1;                 // NTOT
    int*   part  = cur + NTOT;                      // 1024
    int*   ccol  = part + 1024;                     // NEDGE
    float* cval  = (float*)(ccol + NEDGE);          // NEDGE

    hipMemsetAsync(cnt, 0, NTOT * sizeof(int), stream);
    k_init<<<(NTOT * 16 + 255) / 256, 256, 0, stream>>>(ue, ie, E, out);
    k_hist<<<(NEDGE + 255) / 256, 256, 0, stream>>>(erow, cnt);
    k_scan_a<<<NBLK, 256, 0, stream>>>(cnt, part);
    k_scan_b<<<1, 1024, 0, stream>>>(part);
    k_scan_c<<<NBLK, 256, 0, stream>>>(cnt, part, offs, cur);
    k_scatter<<<(NEDGE + 255) / 256, 256, 0, stream>>>(erow, ecol, eval, cur, ccol, cval);

    for (int i = 0; i < 3; i++) {
        k_spmm<<<(NTOT + 3) / 4, 256, 0, stream>>>(E, offs, ccol, cval, front);
        k_rowmv<<<(NTOT + 255) / 256, 256, 0, stream>>>(
            front, E, Wf + (size_t)i * D * D, bfv + (size_t)i * D,
            Wb + (size_t)i * D * D, bbv + (size_t)i * D, out, i + 1);
    }
}

// Round 2
// 1594.176 us; speedup vs baseline: 1.1382x; 1.1382x over previous
//
#include <hip/hip_runtime.h>
#include <hip/hip_bf16.h>
#include <stdint.h>

#define N_USER 100000
#define N_ITEM 50000
#define NTOT   150000
#define NEDGE  1200000
#define D      64
#define OUTD   256
#define NEG    0.01f
#define NBLK   586   // ceil(150000/256)

// Build E = concat(user_emb, item_emb) and write output chunk 0 (raw emb, fp32)
__global__ void k_init(const float* __restrict__ ue, const float* __restrict__ ie,
                       float* __restrict__ E, float* __restrict__ out) {
    int t = blockIdx.x * blockDim.x + threadIdx.x;
    if (t >= NTOT * 16) return;
    int r = t >> 4, q = t & 15;
    const float* src = (r < N_USER) ? (ue + (size_t)r * D)
                                    : (ie + (size_t)(r - N_USER) * D);
    float4 v = *(const float4*)(src + q * 4);
    *(float4*)(E + (size_t)r * D + q * 4) = v;
    *(float4*)(out + (size_t)r * OUTD + q * 4) = v;
}

__global__ void k_hist(const int* __restrict__ row, int* __restrict__ cnt) {
    int e = blockIdx.x * blockDim.x + threadIdx.x;
    if (e < NEDGE) atomicAdd(&cnt[row[e]], 1);
}

// Phase A: per-block (256) partial sums of counts
__global__ void k_scan_a(const int* __restrict__ cnt, int* __restrict__ part) {
    __shared__ int s[4];
    int i = blockIdx.x * 256 + threadIdx.x;
    int v = (i < NTOT) ? cnt[i] : 0;
    for (int off = 32; off; off >>= 1) v += __shfl_down(v, off, 64);
    if ((threadIdx.x & 63) == 0) s[threadIdx.x >> 6] = v;
    __syncthreads();
    if (threadIdx.x == 0) part[blockIdx.x] = s[0] + s[1] + s[2] + s[3];
}

// Phase B: single-block exclusive scan of NBLK partials
__global__ void k_scan_b(int* __restrict__ part) {
    __shared__ int s[1024];
    int t = threadIdx.x;
    int v = (t < NBLK) ? part[t] : 0;
    s[t] = v;
    __syncthreads();
    for (int off = 1; off < 1024; off <<= 1) {
        int x = (t >= off) ? s[t - off] : 0;
        __syncthreads();
        s[t] += x;
        __syncthreads();
    }
    if (t < NBLK) part[t] = s[t] - v;  // exclusive
}

// Phase C: in-block exclusive scan + block base -> offsets and cursor copy
__global__ void k_scan_c(const int* __restrict__ cnt, const int* __restrict__ part,
                         int* __restrict__ offs, int* __restrict__ cur) {
    __shared__ int ws[4];
    int i = blockIdx.x * 256 + threadIdx.x;
    int v = (i < NTOT) ? cnt[i] : 0;
    int lane = threadIdx.x & 63, w = threadIdx.x >> 6;
    int x = v;
    for (int o = 1; o < 64; o <<= 1) {
        int y = __shfl_up(x, o, 64);
        if (lane >= o) x += y;
    }
    if (lane == 63) ws[w] = x;
    __syncthreads();
    int base = part[blockIdx.x];
    for (int k = 0; k < w; k++) base += ws[k];
    int excl = base + x - v;
    if (i < NTOT) { offs[i] = excl; cur[i] = excl; }
    if (i == 0) offs[NTOT] = NEDGE;
}

__global__ void k_scatter(const int* __restrict__ row, const int* __restrict__ col,
                          const float* __restrict__ val, int* __restrict__ cur,
                          int* __restrict__ ccol, float* __restrict__ cval) {
    int e = blockIdx.x * blockDim.x + threadIdx.x;
    if (e >= NEDGE) return;
    int r = row[e];
    int p = atomicAdd(&cur[r], 1);
    ccol[p] = col[e];
    cval[p] = val[e];
}

// front = (H + I) @ E : wave per row, lane per dim
__global__ void k_spmm(const float* __restrict__ E, const int* __restrict__ offs,
                       const int* __restrict__ ccol, const float* __restrict__ cval,
                       float* __restrict__ front) {
    int r = blockIdx.x * (blockDim.x >> 6) + (threadIdx.x >> 6);
    int d = threadIdx.x & 63;
    if (r >= NTOT) return;
    int s = offs[r], e = offs[r + 1];
    float acc = E[(size_t)r * D + d];
    for (int p = s; p < e; ++p) {
        int   c = ccol[p];
        float v = cval[p];
        acc += v * E[(size_t)c * D + d];
    }
    front[(size_t)r * D + d] = acc;
}

// Per-row: fc = lrelu(front@Wf^T + bf); back = lrelu((E*front)@Wb^T + bb);
// E_new = fc + back (in place, UNNORMALIZED for next layer);
// out chunk = E_new / max(||E_new||, eps).
//
// Round-4 lesson (rocprof): per-thread f[64]+g[64] (=128 floats) loses to the
// allocator's occupancy heuristic (it capped at 128 VGPR and scratch'd the
// arrays: FETCH 188MB, 395us). Fix: 4 LANES PER ROW. Lane role q=lane&3 owns
// a 16-elem K-quarter (f[16]+g[16] = 32 floats). Each output j: per-lane
// partial dot + 2-step __shfl_xor quad reduce -> all 4 lanes hold the full
// sum; bias+lrelu+nsq computed redundantly (identical across quad). q==0
// lane stores the unnormalized float4 per j4-block to E; epilogue re-reads
// the L1-hot E row to write the normalized out chunk. No runtime-indexed
// arrays -> zero scratch. Weight reads are 4-address 16-lane broadcasts
// (64B contiguous per wave), L1-resident (both W = 32KB).
__global__ __launch_bounds__(256, 4) void k_rowmv(
    const float* __restrict__ front, float* __restrict__ E,
    const float* __restrict__ Wf, const float* __restrict__ bfv,
    const float* __restrict__ Wb, const float* __restrict__ bbv,
    float* __restrict__ out, int chunk) {
    int lane = threadIdx.x & 63;
    int w    = threadIdx.x >> 6;
    int q    = lane & 3;        // K-quarter role
    int g    = lane >> 2;       // row-in-wave (0..15)
    int r    = blockIdx.x * 64 + w * 16 + g;
    if (r >= NTOT) return;

    // Load this lane's K-quarter of front (f) and E*front (gg)
    float f[16], gg[16];
    const float* fp = front + (size_t)r * D + q * 16;
    const float* ep = E     + (size_t)r * D + q * 16;
    #pragma unroll
    for (int i = 0; i < 4; i++) {
        float4 a = *(const float4*)(fp + i * 4);
        float4 b = *(const float4*)(ep + i * 4);
        f[i*4+0] = a.x; f[i*4+1] = a.y; f[i*4+2] = a.z; f[i*4+3] = a.w;
        gg[i*4+0] = a.x*b.x; gg[i*4+1] = a.y*b.y; gg[i*4+2] = a.z*b.z; gg[i*4+3] = a.w*b.w;
    }

    float nsq = 0.f;
    float* erow = E + (size_t)r * D;
    #pragma unroll 1
    for (int j4 = 0; j4 < 16; j4++) {
        float e4[4];
        #pragma unroll
        for (int jj = 0; jj < 4; jj++) {
            int j = j4 * 4 + jj;
            const float* wf = Wf + (size_t)j * D + q * 16;
            const float* wb = Wb + (size_t)j * D + q * 16;
            float aF = 0.f, aB = 0.f;
            #pragma unroll
            for (int i = 0; i < 4; i++) {
                float4 wv = *(const float4*)(wf + i * 4);
                aF = fmaf(wv.x, f[i*4+0], aF);
                aF = fmaf(wv.y, f[i*4+1], aF);
                aF = fmaf(wv.z, f[i*4+2], aF);
                aF = fmaf(wv.w, f[i*4+3], aF);
                float4 bv = *(const float4*)(wb + i * 4);
                aB = fmaf(bv.x, gg[i*4+0], aB);
                aB = fmaf(bv.y, gg[i*4+1], aB);
                aB = fmaf(bv.z, gg[i*4+2], aB);
                aB = fmaf(bv.w, gg[i*4+3], aB);
            }
            // quad tree-reduce: all 4 lanes end with the full K=64 sum
            aF += __shfl_xor(aF, 1, 64);
            aF += __shfl_xor(aF, 2, 64);
            aB += __shfl_xor(aB, 1, 64);
            aB += __shfl_xor(aB, 2, 64);
            aF += bfv[j];
            aB += bbv[j];
            float vF = (aF > 0.f) ? aF : NEG * aF;
            float vB = (aB > 0.f) ? aB : NEG * aB;
            float e = vF + vB;
            e4[jj] = e;          // static index after unroll
            nsq += e * e;        // identical across the quad -> exact row norm
        }
        if (q == 0) {
            float4 u;
            u.x = e4[0]; u.y = e4[1]; u.z = e4[2]; u.w = e4[3];
            *(float4*)(erow + j4 * 4) = u;   // unnormalized E for next layer
        }
    }

    float inv = 1.0f / fmaxf(sqrtf(nsq), 1e-12f);
    // Re-read the just-written row (L1/L2-hot) and emit normalized out chunk.
    float* orow = out + (size_t)r * OUTD + (size_t)chunk * D;
    #pragma unroll
    for (int i = 0; i < 4; i++) {
        float4 u = *(const float4*)(erow + q * 16 + i * 4);
        float4 o;
        o.x = u.x * inv; o.y = u.y * inv; o.z = u.z * inv; o.w = u.w * inv;
        *(float4*)(orow + q * 16 + i * 4) = o;
    }
}

extern "C" void kernel_launch(void* const* d_in, const int* in_sizes, int n_in,
                              void* d_out, int out_size, void* d_ws, size_t ws_size,
                              hipStream_t stream) {
    const float* ue   = (const float*)d_in[0];
    const float* ie   = (const float*)d_in[1];
    const int*   erow = (const int*)d_in[2];
    const int*   ecol = (const int*)d_in[3];
    const float* eval = (const float*)d_in[4];
    const float* Wf   = (const float*)d_in[5];
    const float* bfv  = (const float*)d_in[6];
    const float* Wb   = (const float*)d_in[7];
    const float* bbv  = (const float*)d_in[8];
    float* out = (float*)d_out;

    float* E     = (float*)d_ws;                    // NTOT*D
    float* front = E + (size_t)NTOT * D;            // NTOT*D
    float* invn  = front + (size_t)NTOT * D;        // NTOT (unused now, kept for layout)
    int*   cnt   = (int*)(invn + NTOT);             // NTOT
    int*   offs  = cnt + NTOT;                      // NTOT+1
    int*   cur   = offs + NTOT + 1;                 // NTOT
    int*   part  = cur + NTOT;                      // 1024
    int*   ccol  = part + 1024;                     // NEDGE
    float* cval  = (float*)(ccol + NEDGE);          // NEDGE

    hipMemsetAsync(cnt, 0, NTOT * sizeof(int), stream);
    k_init<<<(NTOT * 16 + 255) / 256, 256, 0, stream>>>(ue, ie, E, out);
    k_hist<<<(NEDGE + 255) / 256, 256, 0, stream>>>(erow, cnt);
    k_scan_a<<<NBLK, 256, 0, stream>>>(cnt, part);
    k_scan_b<<<1, 1024, 0, stream>>>(part);
    k_scan_c<<<NBLK, 256, 0, stream>>>(cnt, part, offs, cur);
    k_scatter<<<(NEDGE + 255) / 256, 256, 0, stream>>>(erow, ecol, eval, cur, ccol, cval);

    for (int i = 0; i < 3; i++) {
        k_spmm<<<(NTOT + 3) / 4, 256, 0, stream>>>(E, offs, ccol, cval, front);
        k_rowmv<<<(NTOT + 63) / 64, 256, 0, stream>>>(
            front, E, Wf + (size_t)i * D * D, bfv + (size_t)i * D,
            Wb + (size_t)i * D * D, bbv + (size_t)i * D, out, i + 1);
    }
}